// Round 2
// baseline (710.625 us; speedup 1.0000x reference)
//
#include <hip/hip_runtime.h>
#include <stdint.h>

#define DD 2048   // hidden
#define HH 1408   // intermediate
#define EE 8      // experts
#define TT 4096   // tokens (B*S)

#define BM 128
#define BN 64
#define BK 64
#define MAXBLK 72   // >= max live m-blocks = 64 + 7 rounding
#define NB1 22      // HH / BN
#define NB2 32      // DD / BN
#define NW8 2883584 // EE*HH*DD/8

using floatx4 = __attribute__((ext_vector_type(4))) float;
using bf16x8  = __attribute__((ext_vector_type(8))) __bf16;

// round-half-up fp32->bf16 pair pack: result = (bf(b)<<16)|bf(a)
__device__ __forceinline__ unsigned int pack_bf16(float a, float b) {
    unsigned int ua = __float_as_uint(a) + 0x8000u;
    unsigned int ub = __float_as_uint(b) + 0x8000u;
    return __builtin_amdgcn_perm(ub, ua, 0x07060302u);
}
__device__ __forceinline__ unsigned short f2bf(float a) {
    return (unsigned short)((__float_as_uint(a) + 0x8000u) >> 16);
}

// async global->LDS, 16B per lane; LDS dest = base + lane*16 (wave-uniform base)
__device__ __forceinline__ void gld16(const unsigned short* g, unsigned short* l) {
    __builtin_amdgcn_global_load_lds(
        (__attribute__((address_space(1))) void*)g,
        (__attribute__((address_space(3))) void*)l, 16, 0, 0);
}

// bijective XCD swizzle over [0, live): consecutive work ids land on one XCD
__device__ __forceinline__ int xcd_swz(int bid, int live) {
    int xcd = bid & 7, pos = bid >> 3;
    int q = live >> 3, r = live & 7;
    return (xcd < r ? xcd * (q + 1) : r * (q + 1) + (xcd - r) * q) + pos;
}

// ---------------- prep: zero counts/cursors + fp32->bf16 convert of W1/W3/W2 ----------------
__global__ __launch_bounds__(256) void k_prep(const float* __restrict__ W1,
                                              const float* __restrict__ W3,
                                              const float* __restrict__ W2,
                                              unsigned short* __restrict__ W1b,
                                              unsigned short* __restrict__ W3b,
                                              unsigned short* __restrict__ W2b,
                                              int* __restrict__ counts,
                                              int* __restrict__ cursor) {
    if (blockIdx.x == 0 && threadIdx.x < 16) {
        if (threadIdx.x < 8) counts[threadIdx.x] = 0;
        else                 cursor[threadIdx.x - 8] = 0;
    }
    int i = blockIdx.x * 256 + threadIdx.x;
    if (i >= 3 * NW8) return;
    const float* s; unsigned short* d; int off;
    if (i < NW8)          { s = W1; d = W1b; off = i; }
    else if (i < 2 * NW8) { s = W3; d = W3b; off = i - NW8; }
    else                  { s = W2; d = W2b; off = i - 2 * NW8; }
    const float4* s4 = (const float4*)s + (size_t)off * 2;
    float4 a = s4[0], b = s4[1];
    uint4 o;
    o.x = pack_bf16(a.x, a.y); o.y = pack_bf16(a.z, a.w);
    o.z = pack_bf16(b.x, b.y); o.w = pack_bf16(b.z, b.w);
    *(uint4*)(d + (size_t)off * 8) = o;
}

// ---------------- gate: logits/softmax/top-2 + X->bf16 row + residual row ----------------
__global__ __launch_bounds__(256) void k_gate(const float* __restrict__ x,
                                              const float* __restrict__ Wg,
                                              unsigned short* __restrict__ Xb,
                                              float* __restrict__ out,
                                              int* __restrict__ topk_i,
                                              float* __restrict__ topk_w,
                                              int* __restrict__ counts) {
    const int t = blockIdx.x;
    const int tid = threadIdx.x;
    const float4* xr = (const float4*)(x + (size_t)t * DD);
    float4* orow = (float4*)(out + (size_t)t * DD);
    uint2* xbrow = (uint2*)(Xb + (size_t)t * DD);
    const float4* wg4 = (const float4*)Wg;
    float p[EE];
#pragma unroll
    for (int e = 0; e < EE; ++e) p[e] = 0.f;
#pragma unroll
    for (int it = 0; it < (DD / 4) / 256; ++it) {
        int d4 = it * 256 + tid;
        float4 xv = xr[d4];
        orow[d4] = xv;                                // residual init: out = x
        uint2 pk;
        pk.x = pack_bf16(xv.x, xv.y);
        pk.y = pack_bf16(xv.z, xv.w);
        xbrow[d4] = pk;                               // bf16 activation row
#pragma unroll
        for (int e = 0; e < EE; ++e) {
            float4 wv = wg4[e * (DD / 4) + d4];
            p[e] += xv.x * wv.x + xv.y * wv.y + xv.z * wv.z + xv.w * wv.w;
        }
    }
#pragma unroll
    for (int e = 0; e < EE; ++e) {
#pragma unroll
        for (int off = 32; off; off >>= 1) p[e] += __shfl_xor(p[e], off);
    }
    __shared__ float red[4][EE];
    const int wave = tid >> 6, lane = tid & 63;
    if (lane == 0) {
#pragma unroll
        for (int e = 0; e < EE; ++e) red[wave][e] = p[e];
    }
    __syncthreads();
    if (tid == 0) {
        float lg[EE];
#pragma unroll
        for (int e = 0; e < EE; ++e) lg[e] = red[0][e] + red[1][e] + red[2][e] + red[3][e];
        float mx = lg[0];
#pragma unroll
        for (int e = 1; e < EE; ++e) mx = fmaxf(mx, lg[e]);
        float den = 0.f, pr[EE];
#pragma unroll
        for (int e = 0; e < EE; ++e) { pr[e] = __expf(lg[e] - mx); den += pr[e]; }
        float inv = 1.f / den;
#pragma unroll
        for (int e = 0; e < EE; ++e) pr[e] *= inv;
        int i0 = 0; float v0 = pr[0];
#pragma unroll
        for (int e = 1; e < EE; ++e) if (pr[e] > v0) { v0 = pr[e]; i0 = e; }
        int i1 = -1; float v1 = -1.f;
#pragma unroll
        for (int e = 0; e < EE; ++e) if (e != i0 && pr[e] > v1) { v1 = pr[e]; i1 = e; }
        topk_i[t * 2 + 0] = i0; topk_i[t * 2 + 1] = i1;
        topk_w[t * 2 + 0] = v0; topk_w[t * 2 + 1] = v1;
        atomicAdd(&counts[i0], 1);
        atomicAdd(&counts[i1], 1);
    }
}

// ---------------- scan + live-block table (BM=128 blocks) ----------------
__global__ void k_scan(const int* __restrict__ counts, int* __restrict__ offs,
                       int* __restrict__ blk_e, int* __restrict__ blk_m,
                       int* __restrict__ nblk) {
    if (threadIdx.x == 0) {
        int s = 0, nb = 0;
        for (int e = 0; e < EE; ++e) {
            offs[e] = s;
            int c = counts[e];
            for (int m = 0; m < c; m += BM) { blk_e[nb] = e; blk_m[nb] = m; ++nb; }
            s += c;
        }
        *nblk = nb;
        for (int i = nb; i < MAXBLK; ++i) { blk_e[i] = 0; blk_m[i] = 0; }
    }
}

// ---------------- compact ----------------
__global__ __launch_bounds__(256) void k_compact(const int* __restrict__ topk_i,
                                                 const float* __restrict__ topk_w,
                                                 const int* __restrict__ offs,
                                                 int* __restrict__ cursor,
                                                 int* __restrict__ tok_id,
                                                 float* __restrict__ tok_w) {
    const int t = blockIdx.x * 256 + threadIdx.x;
    if (t >= TT) return;
#pragma unroll
    for (int k = 0; k < 2; ++k) {
        int e = topk_i[t * 2 + k];
        int slot = atomicAdd(&cursor[e], 1);
        int p = offs[e] + slot;
        tok_id[p] = t;
        tok_w[p] = topk_w[t * 2 + k];
    }
}

// ---------------- gemm1: h = silu(X@W1^T) * (X@W3^T), 2-phase dbuf prefetch ----------------
__global__ __launch_bounds__(256, 2) void k_gemm1(const unsigned short* __restrict__ Xb,
                                                  const unsigned short* __restrict__ W1b,
                                                  const unsigned short* __restrict__ W3b,
                                                  const int* __restrict__ counts,
                                                  const int* __restrict__ offs,
                                                  const int* __restrict__ blk_e,
                                                  const int* __restrict__ blk_m,
                                                  const int* __restrict__ nblk,
                                                  const int* __restrict__ tok_id,
                                                  unsigned short* __restrict__ hbuf) {
    const int live = *nblk * NB1;
    int bid = blockIdx.x;
    if (bid >= live) return;
    bid = xcd_swz(bid, live);
    const int b   = bid / NB1;
    const int e   = blk_e[b];
    const int m0  = blk_m[b];
    const int cnt = counts[e];
    const int n0  = (bid % NB1) * BN;
    const int seg = offs[e];
    const int tid = threadIdx.x;

    __shared__ __align__(16) unsigned short Xs[2][BM * 64];   // 2 x 16 KB, swizzled rows
    __shared__ __align__(16) unsigned short W1s[2][BN * 64];  // 2 x 8 KB
    __shared__ __align__(16) unsigned short W3s[2][BN * 64];  // 2 x 8 KB
    __shared__ int ids[BM];

    if (tid < BM) ids[tid] = tok_id[seg + min(m0 + tid, cnt - 1)];
    __syncthreads();

    const int lane = tid & 63, wave = tid >> 6;
    const int lr = lane >> 3, lc = lane & 7;       // staging: row-in-8, chunk slot
    const int quad = lane >> 4, l16 = lane & 15;
    const int wm = wave >> 1, wn = wave & 1;       // 2M x 2N wave grid

    // per-lane global pointers (swizzle applied on the global side)
    const unsigned short* xp[4];
#pragma unroll
    for (int j = 0; j < 4; ++j) {
        int rl = wave * 32 + j * 8 + lr;
        xp[j] = Xb + (size_t)ids[rl] * DD + (lc ^ (rl & 7)) * 8;
    }
    const unsigned short* w1p[2];
    const unsigned short* w3p[2];
#pragma unroll
    for (int j = 0; j < 2; ++j) {
        int rl = wave * 16 + j * 8 + lr;
        size_t ro = ((size_t)e * HH + n0 + rl) * DD + (lc ^ (rl & 7)) * 8;
        w1p[j] = W1b + ro;
        w3p[j] = W3b + ro;
    }

    floatx4 acc1[4][2], acc3[4][2];
#pragma unroll
    for (int i = 0; i < 4; ++i)
#pragma unroll
        for (int j = 0; j < 2; ++j) { acc1[i][j] = (floatx4)(0.f); acc3[i][j] = (floatx4)(0.f); }

    auto stage = [&](int buf, int k0) {
#pragma unroll
        for (int j = 0; j < 4; ++j)
            gld16(xp[j] + k0, &Xs[buf][(wave * 32 + j * 8) * 64]);
#pragma unroll
        for (int j = 0; j < 2; ++j) {
            gld16(w1p[j] + k0, &W1s[buf][(wave * 16 + j * 8) * 64]);
            gld16(w3p[j] + k0, &W3s[buf][(wave * 16 + j * 8) * 64]);
        }
    };

    stage(0, 0);
    __syncthreads();      // buf0 staged
    int cur = 0;
    for (int k0 = 0; k0 < DD; k0 += BK) {
        if (k0 + BK < DD) stage(cur ^ 1, k0 + BK);   // prefetch next tile; lands under compute
#pragma unroll
        for (int kk = 0; kk < 2; ++kk) {
            bf16x8 a[4], b1[2], b3[2];
#pragma unroll
            for (int mf = 0; mf < 4; ++mf) {
                int r = wm * 64 + mf * 16 + l16;
                int s = (quad + kk * 4) ^ (r & 7);
                a[mf] = *(const bf16x8*)&Xs[cur][r * 64 + s * 8];
            }
#pragma unroll
            for (int nf = 0; nf < 2; ++nf) {
                int r = wn * 32 + nf * 16 + l16;
                int s = (quad + kk * 4) ^ (r & 7);
                b1[nf] = *(const bf16x8*)&W1s[cur][r * 64 + s * 8];
                b3[nf] = *(const bf16x8*)&W3s[cur][r * 64 + s * 8];
            }
#pragma unroll
            for (int mf = 0; mf < 4; ++mf)
#pragma unroll
                for (int nf = 0; nf < 2; ++nf) {
                    acc1[mf][nf] = __builtin_amdgcn_mfma_f32_16x16x32_bf16(a[mf], b1[nf], acc1[mf][nf], 0, 0, 0);
                    acc3[mf][nf] = __builtin_amdgcn_mfma_f32_16x16x32_bf16(a[mf], b3[nf], acc3[mf][nf], 0, 0, 0);
                }
        }
        __syncthreads();   // drains prefetch (vmcnt) + everyone done reading cur
        cur ^= 1;
    }
#pragma unroll
    for (int mf = 0; mf < 4; ++mf)
#pragma unroll
        for (int reg = 0; reg < 4; ++reg) {
            int m = wm * 64 + mf * 16 + quad * 4 + reg;
            if (m0 + m < cnt) {
                size_t row = (size_t)(seg + m0 + m) * HH + n0 + wn * 32;
#pragma unroll
                for (int nf = 0; nf < 2; ++nf) {
                    float c1 = acc1[mf][nf][reg];
                    float c3 = acc3[mf][nf][reg];
                    float hv = (c1 / (1.f + __expf(-c1))) * c3;
                    hbuf[row + nf * 16 + l16] = f2bf(hv);
                }
            }
        }
}

// ---------------- gemm2: out += w * (h @ W2^T), 2-phase dbuf prefetch ----------------
__global__ __launch_bounds__(256, 3) void k_gemm2(const unsigned short* __restrict__ hbuf,
                                                  const unsigned short* __restrict__ W2b,
                                                  const int* __restrict__ counts,
                                                  const int* __restrict__ offs,
                                                  const int* __restrict__ blk_e,
                                                  const int* __restrict__ blk_m,
                                                  const int* __restrict__ nblk,
                                                  const int* __restrict__ tok_id,
                                                  const float* __restrict__ tok_w,
                                                  float* __restrict__ out) {
    const int live = *nblk * NB2;
    int bid = blockIdx.x;
    if (bid >= live) return;
    bid = xcd_swz(bid, live);
    const int b   = bid / NB2;
    const int e   = blk_e[b];
    const int m0  = blk_m[b];
    const int cnt = counts[e];
    const int n0  = (bid % NB2) * BN;   // over D
    const int seg = offs[e];
    const int tid = threadIdx.x;

    __shared__ __align__(16) unsigned short As[2][BM * 64];   // 2 x 16 KB
    __shared__ __align__(16) unsigned short Bs[2][BN * 64];   // 2 x 8 KB
    __shared__ int ids[BM];
    __shared__ float wts[BM];

    if (tid < BM) {
        int rc = min(m0 + tid, cnt - 1);
        ids[tid] = tok_id[seg + rc];
        wts[tid] = tok_w[seg + rc];
    }
    __syncthreads();

    const int lane = tid & 63, wave = tid >> 6;
    const int lr = lane >> 3, lc = lane & 7;
    const int quad = lane >> 4, l16 = lane & 15;
    const int wm = wave >> 1, wn = wave & 1;

    const unsigned short* ap[4];
#pragma unroll
    for (int j = 0; j < 4; ++j) {
        int rl = wave * 32 + j * 8 + lr;
        ap[j] = hbuf + (size_t)(seg + min(m0 + rl, cnt - 1)) * HH + (lc ^ (rl & 7)) * 8;
    }
    const unsigned short* bp[2];
#pragma unroll
    for (int j = 0; j < 2; ++j) {
        int rl = wave * 16 + j * 8 + lr;
        bp[j] = W2b + ((size_t)e * DD + n0 + rl) * HH + (lc ^ (rl & 7)) * 8;
    }

    floatx4 acc[4][2];
#pragma unroll
    for (int i = 0; i < 4; ++i)
#pragma unroll
        for (int j = 0; j < 2; ++j) acc[i][j] = (floatx4)(0.f);

    auto stage = [&](int buf, int k0) {
#pragma unroll
        for (int j = 0; j < 4; ++j)
            gld16(ap[j] + k0, &As[buf][(wave * 32 + j * 8) * 64]);
#pragma unroll
        for (int j = 0; j < 2; ++j)
            gld16(bp[j] + k0, &Bs[buf][(wave * 16 + j * 8) * 64]);
    };

    stage(0, 0);
    __syncthreads();
    int cur = 0;
    for (int k0 = 0; k0 < HH; k0 += BK) {
        if (k0 + BK < HH) stage(cur ^ 1, k0 + BK);
#pragma unroll
        for (int kk = 0; kk < 2; ++kk) {
            bf16x8 a[4], bb[2];
#pragma unroll
            for (int mf = 0; mf < 4; ++mf) {
                int r = wm * 64 + mf * 16 + l16;
                int s = (quad + kk * 4) ^ (r & 7);
                a[mf] = *(const bf16x8*)&As[cur][r * 64 + s * 8];
            }
#pragma unroll
            for (int nf = 0; nf < 2; ++nf) {
                int r = wn * 32 + nf * 16 + l16;
                int s = (quad + kk * 4) ^ (r & 7);
                bb[nf] = *(const bf16x8*)&Bs[cur][r * 64 + s * 8];
            }
#pragma unroll
            for (int mf = 0; mf < 4; ++mf)
#pragma unroll
                for (int nf = 0; nf < 2; ++nf)
                    acc[mf][nf] = __builtin_amdgcn_mfma_f32_16x16x32_bf16(a[mf], bb[nf], acc[mf][nf], 0, 0, 0);
        }
        __syncthreads();
        cur ^= 1;
    }
#pragma unroll
    for (int mf = 0; mf < 4; ++mf)
#pragma unroll
        for (int reg = 0; reg < 4; ++reg) {
            int m = wm * 64 + mf * 16 + quad * 4 + reg;
            if (m0 + m < cnt) {
                int token = ids[m];
                float w = wts[m];
                float* orow = out + (size_t)token * DD + n0 + wn * 32;
#pragma unroll
                for (int nf = 0; nf < 2; ++nf)
                    atomicAdd(orow + nf * 16 + l16, w * acc[mf][nf][reg]);
            }
        }
}

extern "C" void kernel_launch(void* const* d_in, const int* in_sizes, int n_in,
                              void* d_out, int out_size, void* d_ws, size_t ws_size,
                              hipStream_t stream) {
    const float* x  = (const float*)d_in[0];
    const float* Wg = (const float*)d_in[1];
    const float* W1 = (const float*)d_in[2];
    const float* W3 = (const float*)d_in[3];
    const float* W2 = (const float*)d_in[4];
    float* out = (float*)d_out;

    int*   counts = (int*)d_ws;
    int*   cursor = counts + 8;
    int*   offs   = cursor + 8;
    int*   blk_e  = offs + 8;
    int*   blk_m  = blk_e + MAXBLK;
    int*   nblk   = blk_m + MAXBLK;
    int*   topk_i = nblk + 8;   // keep alignment slack
    float* topk_w = (float*)(topk_i + 2 * TT);
    int*   tok_id = (int*)(topk_w + 2 * TT);
    float* tok_w  = (float*)(tok_id + 2 * TT);
    unsigned short* hbuf = (unsigned short*)(tok_w + 2 * TT);     // 2T x H bf16
    unsigned short* Xb   = hbuf + (size_t)2 * TT * HH;            // T x D bf16
    unsigned short* W1b  = Xb + (size_t)TT * DD;                  // E x H x D bf16
    unsigned short* W3b  = W1b + (size_t)EE * HH * DD;
    unsigned short* W2b  = W3b + (size_t)EE * HH * DD;            // E x D x H bf16
    // total ws use ~178.4 MB

    k_prep<<<(3 * NW8) / 256, 256, 0, stream>>>(W1, W3, W2, W1b, W3b, W2b, counts, cursor);
    k_gate<<<TT, 256, 0, stream>>>(x, Wg, Xb, out, topk_i, topk_w, counts);
    k_scan<<<1, 64, 0, stream>>>(counts, offs, blk_e, blk_m, nblk);
    k_compact<<<TT / 256, 256, 0, stream>>>(topk_i, topk_w, offs, cursor, tok_id, tok_w);
    k_gemm1<<<MAXBLK * NB1, 256, 0, stream>>>(Xb, W1b, W3b, counts, offs,
                                              blk_e, blk_m, nblk, tok_id, hbuf);
    k_gemm2<<<MAXBLK * NB2, 256, 0, stream>>>(hbuf, W2b, counts, offs,
                                              blk_e, blk_m, nblk, tok_id, tok_w, out);
}

// Round 3
// 687.239 us; speedup vs baseline: 1.0340x; 1.0340x over previous
//
#include <hip/hip_runtime.h>
#include <stdint.h>

#define DD 2048   // hidden
#define HH 1408   // intermediate
#define EE 8      // experts
#define TT 4096   // tokens (B*S)

#define BM 128
#define BK 64
#define MAXBLK 72   // >= max live m-blocks = 64 + 8 rounding
#define NB1 22      // HH / 64 h-cols per block
#define NB2 16      // DD / 128 out-cols per block
#define NW8 2883584 // EE*HH*DD/8

using floatx4 = __attribute__((ext_vector_type(4))) float;
using bf16x8  = __attribute__((ext_vector_type(8))) __bf16;

// round-half-up fp32->bf16 pair pack: result = (bf(b)<<16)|bf(a)
__device__ __forceinline__ unsigned int pack_bf16(float a, float b) {
    unsigned int ua = __float_as_uint(a) + 0x8000u;
    unsigned int ub = __float_as_uint(b) + 0x8000u;
    return __builtin_amdgcn_perm(ub, ua, 0x07060302u);
}
__device__ __forceinline__ unsigned short f2bf(float a) {
    return (unsigned short)((__float_as_uint(a) + 0x8000u) >> 16);
}

// async global->LDS, 16B per lane; LDS dest = base + lane*16 (wave-uniform base)
__device__ __forceinline__ void gld16(const unsigned short* g, unsigned short* l) {
    __builtin_amdgcn_global_load_lds(
        (__attribute__((address_space(1))) void*)g,
        (__attribute__((address_space(3))) void*)l, 16, 0, 0);
}

// bijective XCD swizzle over [0, live): consecutive work ids land on one XCD
__device__ __forceinline__ int xcd_swz(int bid, int live) {
    int xcd = bid & 7, pos = bid >> 3;
    int q = live >> 3, r = live & 7;
    return (xcd < r ? xcd * (q + 1) : r * (q + 1) + (xcd - r) * q) + pos;
}

// ---------------- prep: zero counts/cursors + fp32->bf16 convert of W1/W3/W2 ----------------
__global__ __launch_bounds__(256) void k_prep(const float* __restrict__ W1,
                                              const float* __restrict__ W3,
                                              const float* __restrict__ W2,
                                              unsigned short* __restrict__ W1b,
                                              unsigned short* __restrict__ W3b,
                                              unsigned short* __restrict__ W2b,
                                              int* __restrict__ counts,
                                              int* __restrict__ cursor) {
    if (blockIdx.x == 0 && threadIdx.x < 16) {
        if (threadIdx.x < 8) counts[threadIdx.x] = 0;
        else                 cursor[threadIdx.x - 8] = 0;
    }
    int i = blockIdx.x * 256 + threadIdx.x;
    if (i >= 3 * NW8) return;
    const float* s; unsigned short* d; int off;
    if (i < NW8)          { s = W1; d = W1b; off = i; }
    else if (i < 2 * NW8) { s = W3; d = W3b; off = i - NW8; }
    else                  { s = W2; d = W2b; off = i - 2 * NW8; }
    const float4* s4 = (const float4*)s + (size_t)off * 2;
    float4 a = s4[0], b = s4[1];
    uint4 o;
    o.x = pack_bf16(a.x, a.y); o.y = pack_bf16(a.z, a.w);
    o.z = pack_bf16(b.x, b.y); o.w = pack_bf16(b.z, b.w);
    *(uint4*)(d + (size_t)off * 8) = o;
}

// ---------------- gate: logits/softmax/top-2 + X->bf16 row + residual row ----------------
__global__ __launch_bounds__(256) void k_gate(const float* __restrict__ x,
                                              const float* __restrict__ Wg,
                                              unsigned short* __restrict__ Xb,
                                              float* __restrict__ out,
                                              int* __restrict__ topk_i,
                                              float* __restrict__ topk_w,
                                              int* __restrict__ counts) {
    const int t = blockIdx.x;
    const int tid = threadIdx.x;
    const float4* xr = (const float4*)(x + (size_t)t * DD);
    float4* orow = (float4*)(out + (size_t)t * DD);
    uint2* xbrow = (uint2*)(Xb + (size_t)t * DD);
    const float4* wg4 = (const float4*)Wg;
    float p[EE];
#pragma unroll
    for (int e = 0; e < EE; ++e) p[e] = 0.f;
#pragma unroll
    for (int it = 0; it < (DD / 4) / 256; ++it) {
        int d4 = it * 256 + tid;
        float4 xv = xr[d4];
        orow[d4] = xv;                                // residual init: out = x
        uint2 pk;
        pk.x = pack_bf16(xv.x, xv.y);
        pk.y = pack_bf16(xv.z, xv.w);
        xbrow[d4] = pk;                               // bf16 activation row
#pragma unroll
        for (int e = 0; e < EE; ++e) {
            float4 wv = wg4[e * (DD / 4) + d4];
            p[e] += xv.x * wv.x + xv.y * wv.y + xv.z * wv.z + xv.w * wv.w;
        }
    }
#pragma unroll
    for (int e = 0; e < EE; ++e) {
#pragma unroll
        for (int off = 32; off; off >>= 1) p[e] += __shfl_xor(p[e], off);
    }
    __shared__ float red[4][EE];
    const int wave = tid >> 6, lane = tid & 63;
    if (lane == 0) {
#pragma unroll
        for (int e = 0; e < EE; ++e) red[wave][e] = p[e];
    }
    __syncthreads();
    if (tid == 0) {
        float lg[EE];
#pragma unroll
        for (int e = 0; e < EE; ++e) lg[e] = red[0][e] + red[1][e] + red[2][e] + red[3][e];
        float mx = lg[0];
#pragma unroll
        for (int e = 1; e < EE; ++e) mx = fmaxf(mx, lg[e]);
        float den = 0.f, pr[EE];
#pragma unroll
        for (int e = 0; e < EE; ++e) { pr[e] = __expf(lg[e] - mx); den += pr[e]; }
        float inv = 1.f / den;
#pragma unroll
        for (int e = 0; e < EE; ++e) pr[e] *= inv;
        int i0 = 0; float v0 = pr[0];
#pragma unroll
        for (int e = 1; e < EE; ++e) if (pr[e] > v0) { v0 = pr[e]; i0 = e; }
        int i1 = -1; float v1 = -1.f;
#pragma unroll
        for (int e = 0; e < EE; ++e) if (e != i0 && pr[e] > v1) { v1 = pr[e]; i1 = e; }
        topk_i[t * 2 + 0] = i0; topk_i[t * 2 + 1] = i1;
        topk_w[t * 2 + 0] = v0; topk_w[t * 2 + 1] = v1;
        atomicAdd(&counts[i0], 1);
        atomicAdd(&counts[i1], 1);
    }
}

// ---------------- scan + live-block table (BM=128 blocks) ----------------
__global__ void k_scan(const int* __restrict__ counts, int* __restrict__ offs,
                       int* __restrict__ blk_e, int* __restrict__ blk_m,
                       int* __restrict__ nblk) {
    if (threadIdx.x == 0) {
        int s = 0, nb = 0;
        for (int e = 0; e < EE; ++e) {
            offs[e] = s;
            int c = counts[e];
            for (int m = 0; m < c; m += BM) { blk_e[nb] = e; blk_m[nb] = m; ++nb; }
            s += c;
        }
        *nblk = nb;
        for (int i = nb; i < MAXBLK; ++i) { blk_e[i] = 0; blk_m[i] = 0; }
    }
}

// ---------------- compact ----------------
__global__ __launch_bounds__(256) void k_compact(const int* __restrict__ topk_i,
                                                 const float* __restrict__ topk_w,
                                                 const int* __restrict__ offs,
                                                 int* __restrict__ cursor,
                                                 int* __restrict__ tok_id,
                                                 float* __restrict__ tok_w) {
    const int t = blockIdx.x * 256 + threadIdx.x;
    if (t >= TT) return;
#pragma unroll
    for (int k = 0; k < 2; ++k) {
        int e = topk_i[t * 2 + k];
        int slot = atomicAdd(&cursor[e], 1);
        int p = offs[e] + slot;
        tok_id[p] = t;
        tok_w[p] = topk_w[t * 2 + k];
    }
}

// ---------------- gemm1: h = silu(X@W1^T) * (X@W3^T) ----------------
// m97 shape: 128x128 tile (B-tile = W1/W3 interleaved in 16-row groups),
// BK=64, 4 waves of 64x64, single-buffered LDS, 3+ blocks/CU.
// B group g (16 rows): matrix = g&1 (0=W1,1=W3), h-col block = g>>1.
__global__ __launch_bounds__(256, 3) void k_gemm1(const unsigned short* __restrict__ Xb,
                                                  const unsigned short* __restrict__ W1b,
                                                  const unsigned short* __restrict__ W3b,
                                                  const int* __restrict__ counts,
                                                  const int* __restrict__ offs,
                                                  const int* __restrict__ blk_e,
                                                  const int* __restrict__ blk_m,
                                                  const int* __restrict__ nblk,
                                                  const int* __restrict__ tok_id,
                                                  unsigned short* __restrict__ hbuf) {
    const int live = *nblk * NB1;
    int bid = blockIdx.x;
    if (bid >= live) return;
    bid = xcd_swz(bid, live);
    const int b   = bid / NB1;
    const int e   = blk_e[b];
    const int m0  = blk_m[b];
    const int cnt = counts[e];
    const int n0  = (bid % NB1) * 64;    // h-col base (64 h-cols per block)
    const int seg = offs[e];
    const int tid = threadIdx.x;

    __shared__ __align__(16) unsigned short Xs[BM * 64];   // 16 KB
    __shared__ __align__(16) unsigned short Bs[BM * 64];   // 16 KB (W1/W3 interleaved)
    __shared__ int ids[BM];

    if (tid < BM) ids[tid] = tok_id[seg + min(m0 + tid, cnt - 1)];
    __syncthreads();

    const int lane = tid & 63, wave = tid >> 6;
    const int lr = lane >> 3, lc = lane & 7;       // staging: row-in-8, chunk slot
    const int quad = lane >> 4, l16 = lane & 15;
    const int wm = wave >> 1, wn = wave & 1;       // 2M x 2N wave grid

    // A staging pointers: 4 x (8 rows), rows rl = wave*32 + j*8 + lr
    const unsigned short* xp[4];
#pragma unroll
    for (int j = 0; j < 4; ++j) {
        int rl = wave * 32 + j * 8 + lr;
        xp[j] = Xb + (size_t)ids[rl] * DD + (lc ^ lr) * 8;
    }
    // B staging pointers: wave w owns groups {2w, 2w+1} = W1 (j=0,1) / W3 (j=2,3)
    // of h-cols [n0 + 16w, n0 + 16w + 16)
    const unsigned short* bpp[4];
#pragma unroll
    for (int j = 0; j < 4; ++j) {
        const unsigned short* base = (j < 2) ? W1b : W3b;
        int row = n0 + wave * 16 + (j & 1) * 8 + lr;
        bpp[j] = base + ((size_t)e * HH + row) * DD + (lc ^ lr) * 8;
    }

    floatx4 acc[4][4];
#pragma unroll
    for (int i = 0; i < 4; ++i)
#pragma unroll
        for (int j = 0; j < 4; ++j) acc[i][j] = (floatx4)(0.f);

    for (int k0 = 0; k0 < DD; k0 += BK) {
#pragma unroll
        for (int j = 0; j < 4; ++j)
            gld16(xp[j] + k0, &Xs[(wave * 32 + j * 8) * 64]);
#pragma unroll
        for (int j = 0; j < 4; ++j)
            gld16(bpp[j] + k0, &Bs[(wave * 32 + j * 8) * 64]);
        __syncthreads();
#pragma unroll
        for (int kk = 0; kk < 2; ++kk) {
            bf16x8 a[4], bb[4];
#pragma unroll
            for (int mf = 0; mf < 4; ++mf) {
                int r = wm * 64 + mf * 16 + l16;
                int s = (quad + kk * 4) ^ (r & 7);
                a[mf] = *(const bf16x8*)&Xs[r * 64 + s * 8];
            }
#pragma unroll
            for (int nf = 0; nf < 4; ++nf) {
                int r = wn * 64 + nf * 16 + l16;
                int s = (quad + kk * 4) ^ (r & 7);
                bb[nf] = *(const bf16x8*)&Bs[r * 64 + s * 8];
            }
#pragma unroll
            for (int mf = 0; mf < 4; ++mf)
#pragma unroll
                for (int nf = 0; nf < 4; ++nf)
                    acc[mf][nf] = __builtin_amdgcn_mfma_f32_16x16x32_bf16(a[mf], bb[nf], acc[mf][nf], 0, 0, 0);
        }
        __syncthreads();
    }
    // nf even -> c1 (W1), nf odd -> c3 (W3), same h-cols n0 + (wn*2 + (nf>>1))*16 + l16
#pragma unroll
    for (int mf = 0; mf < 4; ++mf)
#pragma unroll
        for (int reg = 0; reg < 4; ++reg) {
            int m = wm * 64 + mf * 16 + quad * 4 + reg;
            if (m0 + m < cnt) {
                size_t row = (size_t)(seg + m0 + m) * HH + n0 + wn * 32;
                float c1a = acc[mf][0][reg], c3a = acc[mf][1][reg];
                float c1b = acc[mf][2][reg], c3b = acc[mf][3][reg];
                float hva = (c1a / (1.f + __expf(-c1a))) * c3a;
                float hvb = (c1b / (1.f + __expf(-c1b))) * c3b;
                hbuf[row + l16]      = f2bf(hva);
                hbuf[row + 16 + l16] = f2bf(hvb);
            }
        }
}

// ---------------- gemm2: out += w * (h @ W2^T), m97 128x128 shape ----------------
__global__ __launch_bounds__(256, 3) void k_gemm2(const unsigned short* __restrict__ hbuf,
                                                  const unsigned short* __restrict__ W2b,
                                                  const int* __restrict__ counts,
                                                  const int* __restrict__ offs,
                                                  const int* __restrict__ blk_e,
                                                  const int* __restrict__ blk_m,
                                                  const int* __restrict__ nblk,
                                                  const int* __restrict__ tok_id,
                                                  const float* __restrict__ tok_w,
                                                  float* __restrict__ out) {
    const int live = *nblk * NB2;
    int bid = blockIdx.x;
    if (bid >= live) return;
    bid = xcd_swz(bid, live);
    const int b   = bid / NB2;
    const int e   = blk_e[b];
    const int m0  = blk_m[b];
    const int cnt = counts[e];
    const int n0  = (bid % NB2) * 128;   // out-col base over D
    const int seg = offs[e];
    const int tid = threadIdx.x;

    __shared__ __align__(16) unsigned short As[BM * 64];   // 16 KB
    __shared__ __align__(16) unsigned short Bs[BM * 64];   // 16 KB
    __shared__ int ids[BM];
    __shared__ float wts[BM];

    if (tid < BM) {
        int rc = min(m0 + tid, cnt - 1);
        ids[tid] = tok_id[seg + rc];
        wts[tid] = tok_w[seg + rc];
    }
    __syncthreads();

    const int lane = tid & 63, wave = tid >> 6;
    const int lr = lane >> 3, lc = lane & 7;
    const int quad = lane >> 4, l16 = lane & 15;
    const int wm = wave >> 1, wn = wave & 1;

    const unsigned short* ap[4];
#pragma unroll
    for (int j = 0; j < 4; ++j) {
        int rl = wave * 32 + j * 8 + lr;
        ap[j] = hbuf + (size_t)(seg + min(m0 + rl, cnt - 1)) * HH + (lc ^ lr) * 8;
    }
    const unsigned short* bp[4];
#pragma unroll
    for (int j = 0; j < 4; ++j) {
        int row = n0 + wave * 32 + j * 8 + lr;
        bp[j] = W2b + ((size_t)e * DD + row) * HH + (lc ^ lr) * 8;
    }

    floatx4 acc[4][4];
#pragma unroll
    for (int i = 0; i < 4; ++i)
#pragma unroll
        for (int j = 0; j < 4; ++j) acc[i][j] = (floatx4)(0.f);

    for (int k0 = 0; k0 < HH; k0 += BK) {
#pragma unroll
        for (int j = 0; j < 4; ++j)
            gld16(ap[j] + k0, &As[(wave * 32 + j * 8) * 64]);
#pragma unroll
        for (int j = 0; j < 4; ++j)
            gld16(bp[j] + k0, &Bs[(wave * 32 + j * 8) * 64]);
        __syncthreads();
#pragma unroll
        for (int kk = 0; kk < 2; ++kk) {
            bf16x8 a[4], bb[4];
#pragma unroll
            for (int mf = 0; mf < 4; ++mf) {
                int r = wm * 64 + mf * 16 + l16;
                int s = (quad + kk * 4) ^ (r & 7);
                a[mf] = *(const bf16x8*)&As[r * 64 + s * 8];
            }
#pragma unroll
            for (int nf = 0; nf < 4; ++nf) {
                int r = wn * 64 + nf * 16 + l16;
                int s = (quad + kk * 4) ^ (r & 7);
                bb[nf] = *(const bf16x8*)&Bs[r * 64 + s * 8];
            }
#pragma unroll
            for (int mf = 0; mf < 4; ++mf)
#pragma unroll
                for (int nf = 0; nf < 4; ++nf)
                    acc[mf][nf] = __builtin_amdgcn_mfma_f32_16x16x32_bf16(a[mf], bb[nf], acc[mf][nf], 0, 0, 0);
        }
        __syncthreads();
    }
#pragma unroll
    for (int mf = 0; mf < 4; ++mf)
#pragma unroll
        for (int reg = 0; reg < 4; ++reg) {
            int m = wm * 64 + mf * 16 + quad * 4 + reg;
            if (m0 + m < cnt) {
                int token = ids[m];
                float w = wts[m];
                float* orow = out + (size_t)token * DD + n0 + wn * 64;
#pragma unroll
                for (int nf = 0; nf < 4; ++nf)
                    atomicAdd(orow + nf * 16 + l16, w * acc[mf][nf][reg]);
            }
        }
}

extern "C" void kernel_launch(void* const* d_in, const int* in_sizes, int n_in,
                              void* d_out, int out_size, void* d_ws, size_t ws_size,
                              hipStream_t stream) {
    const float* x  = (const float*)d_in[0];
    const float* Wg = (const float*)d_in[1];
    const float* W1 = (const float*)d_in[2];
    const float* W3 = (const float*)d_in[3];
    const float* W2 = (const float*)d_in[4];
    float* out = (float*)d_out;

    int*   counts = (int*)d_ws;
    int*   cursor = counts + 8;
    int*   offs   = cursor + 8;
    int*   blk_e  = offs + 8;
    int*   blk_m  = blk_e + MAXBLK;
    int*   nblk   = blk_m + MAXBLK;
    int*   topk_i = nblk + 8;   // keep alignment slack
    float* topk_w = (float*)(topk_i + 2 * TT);
    int*   tok_id = (int*)(topk_w + 2 * TT);
    float* tok_w  = (float*)(tok_id + 2 * TT);
    unsigned short* hbuf = (unsigned short*)(tok_w + 2 * TT);     // 2T x H bf16
    unsigned short* Xb   = hbuf + (size_t)2 * TT * HH;            // T x D bf16
    unsigned short* W1b  = Xb + (size_t)TT * DD;                  // E x H x D bf16
    unsigned short* W3b  = W1b + (size_t)EE * HH * DD;
    unsigned short* W2b  = W3b + (size_t)EE * HH * DD;            // E x D x H bf16
    // total ws use ~178.4 MB

    k_prep<<<(3 * NW8) / 256, 256, 0, stream>>>(W1, W3, W2, W1b, W3b, W2b, counts, cursor);
    k_gate<<<TT, 256, 0, stream>>>(x, Wg, Xb, out, topk_i, topk_w, counts);
    k_scan<<<1, 64, 0, stream>>>(counts, offs, blk_e, blk_m, nblk);
    k_compact<<<TT / 256, 256, 0, stream>>>(topk_i, topk_w, offs, cursor, tok_id, tok_w);
    k_gemm1<<<MAXBLK * NB1, 256, 0, stream>>>(Xb, W1b, W3b, counts, offs,
                                              blk_e, blk_m, nblk, tok_id, hbuf);
    k_gemm2<<<MAXBLK * NB2, 256, 0, stream>>>(hbuf, W2b, counts, offs,
                                              blk_e, blk_m, nblk, tok_id, tok_w, out);
}